// Round 1
// baseline (421.101 us; speedup 1.0000x reference)
//
#include <hip/hip_runtime.h>
#include <hip/hip_bf16.h>
#include <stdint.h>

typedef __attribute__((ext_vector_type(8))) short short8;
typedef __attribute__((ext_vector_type(4))) float f32x4;

#define K_DIM 4096
#define M_DIM 8192
#define N_DIM 4096

// ---------------------------------------------------------------- helpers
__device__ __forceinline__ void gload_lds16(const void* g, void* l) {
    __builtin_amdgcn_global_load_lds(
        (__attribute__((address_space(1))) void*)(void*)g,
        (__attribute__((address_space(3))) void*)(void*)l,
        16, 0, 0);
}

// exact fp32 -> bf16 truncation: valid because all values are integers
// with |v| <= 256 (<= 8 significant bits), so low 16 bits are zero.
__device__ __forceinline__ unsigned short f32_to_bf16_exact(float f) {
    return (unsigned short)(__float_as_uint(f) >> 16);
}

// ---------------------------------------------------------------- kernel 1: min/max partials
__global__ void minmax_kernel(const float* __restrict__ x, long n4,
                              float* __restrict__ partials) {
    const float4* x4 = (const float4*)x;
    float mn = 1e30f, mx = -1e30f;
    long stride = (long)gridDim.x * blockDim.x;
    for (long i = (long)blockIdx.x * blockDim.x + threadIdx.x; i < n4; i += stride) {
        float4 v = x4[i];
        mn = fminf(mn, fminf(fminf(v.x, v.y), fminf(v.z, v.w)));
        mx = fmaxf(mx, fmaxf(fmaxf(v.x, v.y), fmaxf(v.z, v.w)));
    }
    #pragma unroll
    for (int off = 32; off; off >>= 1) {
        mn = fminf(mn, __shfl_down(mn, off));
        mx = fmaxf(mx, __shfl_down(mx, off));
    }
    __shared__ float smn[4], smx[4];
    int wid = threadIdx.x >> 6, lane = threadIdx.x & 63;
    if (lane == 0) { smn[wid] = mn; smx[wid] = mx; }
    __syncthreads();
    if (threadIdx.x == 0) {
        mn = fminf(fminf(smn[0], smn[1]), fminf(smn[2], smn[3]));
        mx = fmaxf(fmaxf(smx[0], smx[1]), fmaxf(smx[2], smx[3]));
        partials[blockIdx.x] = mn;
        partials[1024 + blockIdx.x] = mx;
    }
}

// ---------------------------------------------------------------- kernel 2: finalize scalars
__global__ void finalize_kernel(const float* __restrict__ partials,
                                const float* __restrict__ wscale,
                                float* __restrict__ scal,
                                float* __restrict__ outscale) {
    float mn = 1e30f, mx = -1e30f;
    for (int i = threadIdx.x; i < 1024; i += 256) {
        mn = fminf(mn, partials[i]);
        mx = fmaxf(mx, partials[1024 + i]);
    }
    #pragma unroll
    for (int off = 32; off; off >>= 1) {
        mn = fminf(mn, __shfl_down(mn, off));
        mx = fmaxf(mx, __shfl_down(mx, off));
    }
    __shared__ float smn[4], smx[4];
    __shared__ float s_scale;
    int wid = threadIdx.x >> 6, lane = threadIdx.x & 63;
    if (lane == 0) { smn[wid] = mn; smx[wid] = mx; }
    __syncthreads();
    if (threadIdx.x == 0) {
        mn = fminf(fminf(smn[0], smn[1]), fminf(smn[2], smn[3]));
        mx = fmaxf(fmaxf(smx[0], smx[1]), fmaxf(smx[2], smx[3]));
        float scale = (mx - mn) / 255.0f;
        float zp = rintf(-128.0f - mn / scale);
        zp = fminf(fmaxf(zp, -128.0f), 127.0f);
        scal[0] = scale;
        scal[1] = zp;
        s_scale = scale;
    }
    __syncthreads();
    float scale = s_scale;
    for (int i = threadIdx.x; i < 4096; i += 256)
        outscale[i] = scale * wscale[i];
}

// ---------------------------------------------------------------- kernel 3: quantize x -> bf16
__global__ void quantize_kernel(const float* __restrict__ x,
                                const float* __restrict__ scal,
                                uint4* __restrict__ A, long n8) {
    float scale = scal[0];
    float zp = scal[1];
    long stride = (long)gridDim.x * blockDim.x;
    for (long i = (long)blockIdx.x * blockDim.x + threadIdx.x; i < n8; i += stride) {
        const float4* xp = (const float4*)x + i * 2;
        float4 v0 = xp[0];
        float4 v1 = xp[1];
        float a[8] = {v0.x, v0.y, v0.z, v0.w, v1.x, v1.y, v1.z, v1.w};
        unsigned short r[8];
        #pragma unroll
        for (int j = 0; j < 8; j++) {
            float q = rintf(a[j] / scale + zp) - zp;  // integer-valued, |q| <= 255
            r[j] = f32_to_bf16_exact(q);
        }
        uint4 o;
        o.x = (unsigned)r[0] | ((unsigned)r[1] << 16);
        o.y = (unsigned)r[2] | ((unsigned)r[3] << 16);
        o.z = (unsigned)r[4] | ((unsigned)r[5] << 16);
        o.w = (unsigned)r[6] | ((unsigned)r[7] << 16);
        A[i] = o;
    }
}

// ---------------------------------------------------------------- kernel 4: weight fp32 -> bf16
__global__ void convw_kernel(const float* __restrict__ w,
                             uint4* __restrict__ Wb, long n8) {
    long stride = (long)gridDim.x * blockDim.x;
    for (long i = (long)blockIdx.x * blockDim.x + threadIdx.x; i < n8; i += stride) {
        const float4* wp = (const float4*)w + i * 2;
        float4 v0 = wp[0];
        float4 v1 = wp[1];
        float a[8] = {v0.x, v0.y, v0.z, v0.w, v1.x, v1.y, v1.z, v1.w};
        unsigned short r[8];
        #pragma unroll
        for (int j = 0; j < 8; j++) r[j] = f32_to_bf16_exact(a[j]);
        uint4 o;
        o.x = (unsigned)r[0] | ((unsigned)r[1] << 16);
        o.y = (unsigned)r[2] | ((unsigned)r[3] << 16);
        o.z = (unsigned)r[4] | ((unsigned)r[5] << 16);
        o.w = (unsigned)r[6] | ((unsigned)r[7] << 16);
        Wb[i] = o;
    }
}

// ---------------------------------------------------------------- kernel 5: bf16 GEMM (m97 structure)
// A: [M=8192][K=4096] bf16, W: [N=4096][K=4096] bf16 (B^T layout),
// C[m][n] = sum_k A[m][k]*W[n][k]; epilogue C = acc*outscale[n] + bias[n].
// 128x128 tile, BK=32, 256 threads (4 waves, 2x2), each wave 64x64 via
// 4x4 fragments of mfma_f32_16x16x32_bf16.
#define BM 128
#define BN 128
#define BK 32

__global__ __launch_bounds__(256) void gemm_kernel(
    const short* __restrict__ A,
    const short* __restrict__ W,
    const float* __restrict__ outscale,
    const float* __restrict__ bias,
    float* __restrict__ C) {
    __shared__ short As[BM * BK];  // 8 KB
    __shared__ short Bs[BN * BK];  // 8 KB

    // XCD-aware swizzle (nwg = 2048, divisible by 8)
    int nwg = gridDim.x;
    int cpx = nwg >> 3;
    int bid = blockIdx.x;
    int wg = (bid & 7) * cpx + (bid >> 3);
    int tm = wg >> 5;   // 64 M-tiles
    int tn = wg & 31;   // 32 N-tiles
    int m0 = tm * BM, n0 = tn * BN;

    int t = threadIdx.x;
    int wid = t >> 6, lane = t & 63;
    int wr = wid >> 1, wc = wid & 1;
    int lr = lane & 15, lk = lane >> 4;

    f32x4 acc[4][4];
    #pragma unroll
    for (int i = 0; i < 4; i++)
        #pragma unroll
        for (int j = 0; j < 4; j++)
            acc[i][j] = (f32x4){0.f, 0.f, 0.f, 0.f};

    // staging geometry: thread t loads 8 bf16 (16 B); rows of 32 elements.
    int e0 = t * 8;
    int ar0 = e0 >> 5, ac0 = e0 & 31;   // rounds: rows 0..63
    int ar1 = ar0 + 64;                 // rows 64..127

    const short* Arow0 = A + (long)(m0 + ar0) * K_DIM + ac0;
    const short* Arow1 = A + (long)(m0 + ar1) * K_DIM + ac0;
    const short* Wrow0 = W + (long)(n0 + ar0) * K_DIM + ac0;
    const short* Wrow1 = W + (long)(n0 + ar1) * K_DIM + ac0;

    for (int kt = 0; kt < K_DIM; kt += BK) {
        __syncthreads();
        gload_lds16(Arow0 + kt, &As[e0]);
        gload_lds16(Arow1 + kt, &As[2048 + e0]);
        gload_lds16(Wrow0 + kt, &Bs[e0]);
        gload_lds16(Wrow1 + kt, &Bs[2048 + e0]);
        __syncthreads();

        short8 a[4], b[4];
        #pragma unroll
        for (int i = 0; i < 4; i++)
            a[i] = *(const short8*)&As[(wr * 64 + i * 16 + lr) * BK + lk * 8];
        #pragma unroll
        for (int j = 0; j < 4; j++)
            b[j] = *(const short8*)&Bs[(wc * 64 + j * 16 + lr) * BK + lk * 8];
        #pragma unroll
        for (int i = 0; i < 4; i++)
            #pragma unroll
            for (int j = 0; j < 4; j++)
                acc[i][j] = __builtin_amdgcn_mfma_f32_16x16x32_bf16(a[i], b[j], acc[i][j], 0, 0, 0);
    }

    // epilogue: C/D layout col = lane&15, row = (lane>>4)*4 + reg
    #pragma unroll
    for (int j = 0; j < 4; j++) {
        int col = n0 + wc * 64 + j * 16 + lr;
        float os = outscale[col];
        float bs = bias[col];
        #pragma unroll
        for (int i = 0; i < 4; i++) {
            int rbase = m0 + wr * 64 + i * 16 + lk * 4;
            #pragma unroll
            for (int r = 0; r < 4; r++) {
                C[(long)(rbase + r) * N_DIM + col] = acc[i][j][r] * os + bs;
            }
        }
    }
}

// ---------------------------------------------------------------- launch
extern "C" void kernel_launch(void* const* d_in, const int* in_sizes, int n_in,
                              void* d_out, int out_size, void* d_ws, size_t ws_size,
                              hipStream_t stream) {
    const float* x      = (const float*)d_in[0];  // [4,2048,4096]
    const float* weight = (const float*)d_in[1];  // [4096,4096] int8-valued
    const float* wscale = (const float*)d_in[2];  // [1,1,4096]
    const float* bias   = (const float*)d_in[3];  // [4096]
    float* out = (float*)d_out;                   // [4,2048,4096]

    char* ws = (char*)d_ws;
    short* Abf      = (short*)ws;                                   // 64 MB
    short* Wbf      = (short*)(ws + (size_t)64 * 1024 * 1024);      // 32 MB
    float* partials = (float*)(ws + (size_t)96 * 1024 * 1024);      // 2048 f
    float* scal     = partials + 2048;                              // 2 f
    float* outsc    = scal + 16;                                    // 4096 f

    long n_x = (long)M_DIM * K_DIM;        // 33554432
    long n_w = (long)N_DIM * K_DIM;        // 16777216

    minmax_kernel<<<1024, 256, 0, stream>>>(x, n_x / 4, partials);
    finalize_kernel<<<1, 256, 0, stream>>>(partials, wscale, scal, outsc);
    quantize_kernel<<<2048, 256, 0, stream>>>(x, scal, (uint4*)Abf, n_x / 8);
    convw_kernel<<<1024, 256, 0, stream>>>(weight, (uint4*)Wbf, n_w / 8);

    dim3 grid((M_DIM / BM) * (N_DIM / BN));  // 64*32 = 2048
    gemm_kernel<<<grid, 256, 0, stream>>>(Abf, Wbf, outsc, bias, out);
}

// Round 2
// 328.043 us; speedup vs baseline: 1.2837x; 1.2837x over previous
//
#include <hip/hip_runtime.h>
#include <hip/hip_bf16.h>
#include <stdint.h>

typedef __attribute__((ext_vector_type(8))) short short8;
typedef __attribute__((ext_vector_type(4))) float f32x4;

#define K_DIM 4096
#define M_DIM 8192
#define N_DIM 4096

#define BM 256
#define BN 256
#define BK 32
#define NT (K_DIM / BK)          // 128 K-tiles
#define TILE_SHORTS (BM * BK)    // 8192 shorts = 16 KB per tile buffer

// ---------------------------------------------------------------- helpers
__device__ __forceinline__ void gload_lds16(const void* g, void* l) {
    __builtin_amdgcn_global_load_lds(
        (__attribute__((address_space(1))) void*)(void*)g,
        (__attribute__((address_space(3))) void*)(void*)l,
        16, 0, 0);
}

// exact fp32 -> bf16 truncation: valid because all values are integers
// with |v| <= 256 (<= 8 significant bits), so dropped mantissa bits are zero.
__device__ __forceinline__ unsigned short f32_to_bf16_exact(float f) {
    return (unsigned short)(__float_as_uint(f) >> 16);
}

// ---------------------------------------------------------------- kernel 1: min/max partials
__global__ void minmax_kernel(const float* __restrict__ x, long n4,
                              float* __restrict__ partials) {
    const float4* x4 = (const float4*)x;
    float mn = 1e30f, mx = -1e30f;
    long stride = (long)gridDim.x * blockDim.x;
    for (long i = (long)blockIdx.x * blockDim.x + threadIdx.x; i < n4; i += stride) {
        float4 v = x4[i];
        mn = fminf(mn, fminf(fminf(v.x, v.y), fminf(v.z, v.w)));
        mx = fmaxf(mx, fmaxf(fmaxf(v.x, v.y), fmaxf(v.z, v.w)));
    }
    #pragma unroll
    for (int off = 32; off; off >>= 1) {
        mn = fminf(mn, __shfl_down(mn, off));
        mx = fmaxf(mx, __shfl_down(mx, off));
    }
    __shared__ float smn[4], smx[4];
    int wid = threadIdx.x >> 6, lane = threadIdx.x & 63;
    if (lane == 0) { smn[wid] = mn; smx[wid] = mx; }
    __syncthreads();
    if (threadIdx.x == 0) {
        mn = fminf(fminf(smn[0], smn[1]), fminf(smn[2], smn[3]));
        mx = fmaxf(fmaxf(smx[0], smx[1]), fmaxf(smx[2], smx[3]));
        partials[blockIdx.x] = mn;
        partials[1024 + blockIdx.x] = mx;
    }
}

// ---------------------------------------------------------------- kernel 2: finalize scalars
__global__ void finalize_kernel(const float* __restrict__ partials,
                                const float* __restrict__ wscale,
                                float* __restrict__ scal,
                                float* __restrict__ outscale) {
    float mn = 1e30f, mx = -1e30f;
    for (int i = threadIdx.x; i < 1024; i += 256) {
        mn = fminf(mn, partials[i]);
        mx = fmaxf(mx, partials[1024 + i]);
    }
    #pragma unroll
    for (int off = 32; off; off >>= 1) {
        mn = fminf(mn, __shfl_down(mn, off));
        mx = fmaxf(mx, __shfl_down(mx, off));
    }
    __shared__ float smn[4], smx[4];
    __shared__ float s_scale;
    int wid = threadIdx.x >> 6, lane = threadIdx.x & 63;
    if (lane == 0) { smn[wid] = mn; smx[wid] = mx; }
    __syncthreads();
    if (threadIdx.x == 0) {
        mn = fminf(fminf(smn[0], smn[1]), fminf(smn[2], smn[3]));
        mx = fmaxf(fmaxf(smx[0], smx[1]), fmaxf(smx[2], smx[3]));
        float scale = (mx - mn) / 255.0f;
        float zp = rintf(-128.0f - mn / scale);
        zp = fminf(fmaxf(zp, -128.0f), 127.0f);
        scal[0] = scale;
        scal[1] = zp;
        s_scale = scale;
    }
    __syncthreads();
    float scale = s_scale;
    for (int i = threadIdx.x; i < 4096; i += 256)
        outscale[i] = scale * wscale[i];
}

// ---------------------------------------------------------------- kernel 3: quantize x -> bf16
__global__ void quantize_kernel(const float* __restrict__ x,
                                const float* __restrict__ scal,
                                uint4* __restrict__ A, long n8) {
    float scale = scal[0];
    float zp = scal[1];
    long stride = (long)gridDim.x * blockDim.x;
    for (long i = (long)blockIdx.x * blockDim.x + threadIdx.x; i < n8; i += stride) {
        const float4* xp = (const float4*)x + i * 2;
        float4 v0 = xp[0];
        float4 v1 = xp[1];
        float a[8] = {v0.x, v0.y, v0.z, v0.w, v1.x, v1.y, v1.z, v1.w};
        unsigned short r[8];
        #pragma unroll
        for (int j = 0; j < 8; j++) {
            float q = rintf(a[j] / scale + zp) - zp;  // integer-valued, |q| <= 255
            r[j] = f32_to_bf16_exact(q);
        }
        uint4 o;
        o.x = (unsigned)r[0] | ((unsigned)r[1] << 16);
        o.y = (unsigned)r[2] | ((unsigned)r[3] << 16);
        o.z = (unsigned)r[4] | ((unsigned)r[5] << 16);
        o.w = (unsigned)r[6] | ((unsigned)r[7] << 16);
        A[i] = o;
    }
}

// ---------------------------------------------------------------- kernel 4: weight fp32 -> bf16
__global__ void convw_kernel(const float* __restrict__ w,
                             uint4* __restrict__ Wb, long n8) {
    long stride = (long)gridDim.x * blockDim.x;
    for (long i = (long)blockIdx.x * blockDim.x + threadIdx.x; i < n8; i += stride) {
        const float4* wp = (const float4*)w + i * 2;
        float4 v0 = wp[0];
        float4 v1 = wp[1];
        float a[8] = {v0.x, v0.y, v0.z, v0.w, v1.x, v1.y, v1.z, v1.w};
        unsigned short r[8];
        #pragma unroll
        for (int j = 0; j < 8; j++) r[j] = f32_to_bf16_exact(a[j]);
        uint4 o;
        o.x = (unsigned)r[0] | ((unsigned)r[1] << 16);
        o.y = (unsigned)r[2] | ((unsigned)r[3] << 16);
        o.z = (unsigned)r[4] | ((unsigned)r[5] << 16);
        o.w = (unsigned)r[6] | ((unsigned)r[7] << 16);
        Wb[i] = o;
    }
}

// ---------------------------------------------------------------- kernel 5: bf16 GEMM
// 256x256 tile, BK=32, 512 threads (8 waves 2Mx4N), 3-deep LDS ring with
// counted vmcnt(4) (2-tile-ahead prefetch), one s_barrier per K-tile,
// setprio around MFMA cluster, XOR LDS swizzle (inverse-swz global source,
// swizzled ds_read; global_load_lds dest stays linear).
// Per wave: out 128x64 = acc[8][4] f32x4; 32 mfma_f32_16x16x32_bf16/K-tile.
__global__ __launch_bounds__(512, 2) void gemm_kernel(
    const short* __restrict__ A,
    const short* __restrict__ W,
    const float* __restrict__ outscale,
    const float* __restrict__ bias,
    float* __restrict__ C) {
    extern __shared__ short lds[];
    short* As = lds;                      // 3 * 16 KB
    short* Bs = lds + 3 * TILE_SHORTS;    // 3 * 16 KB

    // XCD-aware swizzle (nwg = 512, divisible by 8)
    int nwg = gridDim.x;
    int cpx = nwg >> 3;
    int bid = blockIdx.x;
    int wg = (bid & 7) * cpx + (bid >> 3);
    int tm = wg >> 4;   // 32 M-tiles
    int tn = wg & 15;   // 16 N-tiles
    int m0 = tm * BM, n0 = tn * BN;

    int t = threadIdx.x;
    int wid = t >> 6, lane = t & 63;
    int wr = wid >> 2, wc = wid & 3;      // 2 x 4 wave grid
    int lr = lane & 15, lk = lane >> 4;
    int sx = (lr >> 1) & 3;               // per-lane swizzle constant
    int ks = (lk ^ sx) * 8;               // swizzled k-slot (shorts)

    // ---- staging geometry: thread t loads 16 B; LDS dest linear t*16 B.
    // LDS byte L = q*8192 + t*16 -> row = q*128 + t/4, phys slot = t&3.
    // logical slot = phys ^ ((row>>1)&3) = (t&3) ^ ((t>>3)&3)  (q-independent)
    int srow = t >> 2;                            // 0..127
    int sslot = (t & 3) ^ ((t >> 3) & 3);
    const short* gA0 = A + (long)(m0 + srow) * K_DIM + sslot * 8;
    const short* gA1 = A + (long)(m0 + 128 + srow) * K_DIM + sslot * 8;
    const short* gB0 = W + (long)(n0 + srow) * K_DIM + sslot * 8;
    const short* gB1 = W + (long)(n0 + 128 + srow) * K_DIM + sslot * 8;
    int ldst = t * 8;                             // short offset in tile (q0)

    f32x4 acc[8][4];
    #pragma unroll
    for (int i = 0; i < 8; i++)
        #pragma unroll
        for (int j = 0; j < 4; j++)
            acc[i][j] = (f32x4){0.f, 0.f, 0.f, 0.f};

    // ---- prologue: stage tile 0 -> buf0, tile 1 -> buf1
    gload_lds16(gA0,      As + ldst);
    gload_lds16(gA1,      As + 4096 + ldst);
    gload_lds16(gB0,      Bs + ldst);
    gload_lds16(gB1,      Bs + 4096 + ldst);
    gload_lds16(gA0 + BK, As + TILE_SHORTS + ldst);
    gload_lds16(gA1 + BK, As + TILE_SHORTS + 4096 + ldst);
    gload_lds16(gB0 + BK, Bs + TILE_SHORTS + ldst);
    gload_lds16(gB1 + BK, Bs + TILE_SHORTS + 4096 + ldst);
    asm volatile("s_waitcnt vmcnt(4)" ::: "memory");   // tile 0 landed
    asm volatile("s_barrier" ::: "memory");            // globalize

    gA0 += 2 * BK; gA1 += 2 * BK; gB0 += 2 * BK; gB1 += 2 * BK;

    int aoff = (wr * 128 + lr) * BK + ks;   // shorts
    int boff = (wc * 64 + lr) * BK + ks;

    int cur = 0;
    for (int kt = 0; kt < NT; ++kt) {
        if (kt < NT - 2) {
            int sb = cur + 2; if (sb >= 3) sb -= 3;
            short* as_d = As + sb * TILE_SHORTS + ldst;
            short* bs_d = Bs + sb * TILE_SHORTS + ldst;
            gload_lds16(gA0, as_d);
            gload_lds16(gA1, as_d + 4096);
            gload_lds16(gB0, bs_d);
            gload_lds16(gB1, bs_d + 4096);
            gA0 += BK; gA1 += BK; gB0 += BK; gB1 += BK;
            asm volatile("s_waitcnt vmcnt(4)" ::: "memory"); // tile kt+1 landed
        } else {
            asm volatile("s_waitcnt vmcnt(0)" ::: "memory"); // drain tail
        }

        const short* as = As + cur * TILE_SHORTS;
        const short* bs = Bs + cur * TILE_SHORTS;
        short8 a[8], b[4];
        #pragma unroll
        for (int m = 0; m < 8; ++m)
            a[m] = *(const short8*)&as[aoff + m * 16 * BK];
        #pragma unroll
        for (int n = 0; n < 4; ++n)
            b[n] = *(const short8*)&bs[boff + n * 16 * BK];

        __builtin_amdgcn_s_setprio(1);
        #pragma unroll
        for (int m = 0; m < 8; ++m)
            #pragma unroll
            for (int n = 0; n < 4; ++n)
                acc[m][n] = __builtin_amdgcn_mfma_f32_16x16x32_bf16(a[m], b[n], acc[m][n], 0, 0, 0);
        __builtin_amdgcn_s_setprio(0);

        asm volatile("s_barrier" ::: "memory");  // all reads of tile kt done
        if (++cur == 3) cur = 0;
    }

    // ---- epilogue: C/D layout col = lane&15, row = (lane>>4)*4 + reg
    #pragma unroll
    for (int j = 0; j < 4; j++) {
        int col = n0 + wc * 64 + j * 16 + lr;
        float os = outscale[col];
        float bs = bias[col];
        #pragma unroll
        for (int i = 0; i < 8; i++) {
            int rbase = m0 + wr * 128 + i * 16 + lk * 4;
            #pragma unroll
            for (int r = 0; r < 4; r++) {
                C[(long)(rbase + r) * N_DIM + col] = acc[i][j][r] * os + bs;
            }
        }
    }
}

// ---------------------------------------------------------------- launch
extern "C" void kernel_launch(void* const* d_in, const int* in_sizes, int n_in,
                              void* d_out, int out_size, void* d_ws, size_t ws_size,
                              hipStream_t stream) {
    const float* x      = (const float*)d_in[0];  // [4,2048,4096]
    const float* weight = (const float*)d_in[1];  // [4096,4096] int8-valued
    const float* wscale = (const float*)d_in[2];  // [1,1,4096]
    const float* bias   = (const float*)d_in[3];  // [4096]
    float* out = (float*)d_out;                   // [4,2048,4096]

    char* ws = (char*)d_ws;
    short* Abf      = (short*)ws;                                   // 64 MB
    short* Wbf      = (short*)(ws + (size_t)64 * 1024 * 1024);      // 32 MB
    float* partials = (float*)(ws + (size_t)96 * 1024 * 1024);      // 2048 f
    float* scal     = partials + 2048;                              // 2 f
    float* outsc    = scal + 16;                                    // 4096 f

    long n_x = (long)M_DIM * K_DIM;        // 33554432
    long n_w = (long)N_DIM * K_DIM;        // 16777216

    minmax_kernel<<<1024, 256, 0, stream>>>(x, n_x / 4, partials);
    finalize_kernel<<<1, 256, 0, stream>>>(partials, wscale, scal, outsc);
    quantize_kernel<<<2048, 256, 0, stream>>>(x, scal, (uint4*)Abf, n_x / 8);
    convw_kernel<<<1024, 256, 0, stream>>>(weight, (uint4*)Wbf, n_w / 8);

    static int lds_bytes = 2 * 3 * TILE_SHORTS * (int)sizeof(short);  // 98304
    (void)hipFuncSetAttribute((const void*)gemm_kernel,
                              hipFuncAttributeMaxDynamicSharedMemorySize,
                              lds_bytes);
    dim3 grid((M_DIM / BM) * (N_DIM / BN));  // 32*16 = 512
    gemm_kernel<<<grid, 512, lds_bytes, stream>>>(Abf, Wbf, outsc, bias, out);
}

// Round 3
// 298.866 us; speedup vs baseline: 1.4090x; 1.0976x over previous
//
#include <hip/hip_runtime.h>
#include <hip/hip_bf16.h>
#include <stdint.h>

typedef __attribute__((ext_vector_type(8))) short short8;
typedef __attribute__((ext_vector_type(4))) float f32x4;

#define K_DIM 4096
#define M_DIM 8192
#define N_DIM 4096

#define BM 256
#define BN 256
#define BK 64
#define K_TILES (K_DIM / BK)     // 64
#define ITERS (K_TILES / 2)      // 32 iterations, 2 K-tiles each

// ---------------------------------------------------------------- helpers
__device__ __forceinline__ void gload_lds16(const void* g, void* l) {
    __builtin_amdgcn_global_load_lds(
        (__attribute__((address_space(1))) void*)(void*)g,
        (__attribute__((address_space(3))) void*)(void*)l,
        16, 0, 0);
}

// exact fp32 -> bf16 truncation: valid because all values are integers
// with |v| <= 256, so dropped mantissa bits are zero.
__device__ __forceinline__ unsigned short f32_to_bf16_exact(float f) {
    return (unsigned short)(__float_as_uint(f) >> 16);
}

// ---------------------------------------------------------------- kernel 1: min/max partials
__global__ void minmax_kernel(const float* __restrict__ x, long n4,
                              float* __restrict__ partials) {
    const float4* x4 = (const float4*)x;
    float mn = 1e30f, mx = -1e30f;
    long stride = (long)gridDim.x * blockDim.x;
    for (long i = (long)blockIdx.x * blockDim.x + threadIdx.x; i < n4; i += stride) {
        float4 v = x4[i];
        mn = fminf(mn, fminf(fminf(v.x, v.y), fminf(v.z, v.w)));
        mx = fmaxf(mx, fmaxf(fmaxf(v.x, v.y), fmaxf(v.z, v.w)));
    }
    #pragma unroll
    for (int off = 32; off; off >>= 1) {
        mn = fminf(mn, __shfl_down(mn, off));
        mx = fmaxf(mx, __shfl_down(mx, off));
    }
    __shared__ float smn[4], smx[4];
    int wid = threadIdx.x >> 6, lane = threadIdx.x & 63;
    if (lane == 0) { smn[wid] = mn; smx[wid] = mx; }
    __syncthreads();
    if (threadIdx.x == 0) {
        mn = fminf(fminf(smn[0], smn[1]), fminf(smn[2], smn[3]));
        mx = fmaxf(fmaxf(smx[0], smx[1]), fmaxf(smx[2], smx[3]));
        partials[blockIdx.x] = mn;
        partials[1024 + blockIdx.x] = mx;
    }
}

// ---------------------------------------------------------------- kernel 2: finalize scalars
__global__ void finalize_kernel(const float* __restrict__ partials,
                                const float* __restrict__ wscale,
                                float* __restrict__ scal,
                                float* __restrict__ outscale) {
    float mn = 1e30f, mx = -1e30f;
    for (int i = threadIdx.x; i < 1024; i += 256) {
        mn = fminf(mn, partials[i]);
        mx = fmaxf(mx, partials[1024 + i]);
    }
    #pragma unroll
    for (int off = 32; off; off >>= 1) {
        mn = fminf(mn, __shfl_down(mn, off));
        mx = fmaxf(mx, __shfl_down(mx, off));
    }
    __shared__ float smn[4], smx[4];
    __shared__ float s_scale;
    int wid = threadIdx.x >> 6, lane = threadIdx.x & 63;
    if (lane == 0) { smn[wid] = mn; smx[wid] = mx; }
    __syncthreads();
    if (threadIdx.x == 0) {
        mn = fminf(fminf(smn[0], smn[1]), fminf(smn[2], smn[3]));
        mx = fmaxf(fmaxf(smx[0], smx[1]), fmaxf(smx[2], smx[3]));
        float scale = (mx - mn) / 255.0f;
        float zp = rintf(-128.0f - mn / scale);
        zp = fminf(fmaxf(zp, -128.0f), 127.0f);
        scal[0] = scale;
        scal[1] = zp;
        s_scale = scale;
    }
    __syncthreads();
    float scale = s_scale;
    for (int i = threadIdx.x; i < 4096; i += 256)
        outscale[i] = scale * wscale[i];
}

// ---------------------------------------------------------------- kernel 3: quantize x -> bf16
__global__ void quantize_kernel(const float* __restrict__ x,
                                const float* __restrict__ scal,
                                uint4* __restrict__ A, long n8) {
    float scale = scal[0];
    float zp = scal[1];
    long stride = (long)gridDim.x * blockDim.x;
    for (long i = (long)blockIdx.x * blockDim.x + threadIdx.x; i < n8; i += stride) {
        const float4* xp = (const float4*)x + i * 2;
        float4 v0 = xp[0];
        float4 v1 = xp[1];
        float a[8] = {v0.x, v0.y, v0.z, v0.w, v1.x, v1.y, v1.z, v1.w};
        unsigned short r[8];
        #pragma unroll
        for (int j = 0; j < 8; j++) {
            float q = rintf(a[j] / scale + zp) - zp;  // integer-valued, |q| <= 255
            r[j] = f32_to_bf16_exact(q);
        }
        uint4 o;
        o.x = (unsigned)r[0] | ((unsigned)r[1] << 16);
        o.y = (unsigned)r[2] | ((unsigned)r[3] << 16);
        o.z = (unsigned)r[4] | ((unsigned)r[5] << 16);
        o.w = (unsigned)r[6] | ((unsigned)r[7] << 16);
        A[i] = o;
    }
}

// ---------------------------------------------------------------- kernel 4: weight fp32 -> bf16
__global__ void convw_kernel(const float* __restrict__ w,
                             uint4* __restrict__ Wb, long n8) {
    long stride = (long)gridDim.x * blockDim.x;
    for (long i = (long)blockIdx.x * blockDim.x + threadIdx.x; i < n8; i += stride) {
        const float4* wp = (const float4*)w + i * 2;
        float4 v0 = wp[0];
        float4 v1 = wp[1];
        float a[8] = {v0.x, v0.y, v0.z, v0.w, v1.x, v1.y, v1.z, v1.w};
        unsigned short r[8];
        #pragma unroll
        for (int j = 0; j < 8; j++) r[j] = f32_to_bf16_exact(a[j]);
        uint4 o;
        o.x = (unsigned)r[0] | ((unsigned)r[1] << 16);
        o.y = (unsigned)r[2] | ((unsigned)r[3] << 16);
        o.z = (unsigned)r[4] | ((unsigned)r[5] << 16);
        o.w = (unsigned)r[6] | ((unsigned)r[7] << 16);
        Wb[i] = o;
    }
}

// ---------------------------------------------------------------- kernel 5: bf16 GEMM, 8-phase
// 256x256 tile, BK=64, 512 threads (8 waves 2Mx4N). LDS: 2 K-tile buffers
// (buf0 = even tiles, buf1 = odd tiles), each A/B split into 2 "units" of
// 128 rows x 64 shorts staged independently. 8 phases per iteration
// (2 K-tiles); per phase: ds_reads + 1 unit stage + barrier + lgkmcnt(0) +
// 16 MFMA quadrant + barrier. vmcnt(6) only at phases 4/8.
// LDS swizzle: 16B-slot ^= (row&7), applied via inverse-permuted global
// source column (stage) + same XOR on ds_read (rule #21-correct).
//
// A LDS row mapping (per buf, per unit): unit = which P-phase reads it:
//   unit0 rows {0-63,128-191} (read at P1/P5), unit1 rows {64-127,192-255}
//   lds row u for global row g: u = (g&63) + (g>=128 ? 64 : 0)
// B LDS: unit = nhalf; row u = (n>>6)*32 + (n&31) for n with that nhalf.
__global__ __launch_bounds__(512, 2) void gemm_kernel(
    const short* __restrict__ A,
    const short* __restrict__ W,
    const float* __restrict__ outscale,
    const float* __restrict__ bias,
    float* __restrict__ C) {
    extern __shared__ short lds[];
    short* As = lds;            // 2 bufs x 16384 shorts (2 units x 128 x 64)
    short* Bs = lds + 32768;    // same

    // XCD-aware swizzle (nwg = 512, divisible by 8)
    int nwg = gridDim.x;
    int cpx = nwg >> 3;
    int bid = blockIdx.x;
    int wg = (bid & 7) * cpx + (bid >> 3);
    int tm = wg >> 4;   // 32 M-tiles
    int tn = wg & 15;   // 16 N-tiles
    int m0 = tm * BM, n0 = tn * BN;

    int t = threadIdx.x;
    int wid = t >> 6, lane = t & 63;
    int wr = wid >> 2, wc = wid & 3;      // 2 x 4 wave grid
    int lr = lane & 15, lk = lane >> 4;
    int ksw0 = ((lk ^ (lr & 7)) * 8);         // khalf 0 swizzled slot (shorts)
    int ksw1 = (((4 + lk) ^ (lr & 7)) * 8);   // khalf 1

    // staging source geometry
    int R0 = t >> 3;                              // 0..63 (lds row, q=0)
    int csw = ((t & 7) ^ ((t >> 3) & 7)) * 8;     // inverse-swizzled source col
    const short* aSrc = A + (long)(m0 + R0) * K_DIM + csw;
    const short* bSrc = W + (long)(n0 + ((R0 >> 5) << 6) + (R0 & 31)) * K_DIM + csw;
    int ldd = t * 8;                              // lds dest (shorts), q=0

#define STAGE_A(BUF, UN, KT) do { \
    const short* _s = aSrc + (long)(UN) * 64 * K_DIM + (long)(KT) * 64; \
    short* _d = As + (BUF) * 16384 + (UN) * 8192 + ldd; \
    gload_lds16(_s, _d); \
    gload_lds16(_s + (long)128 * K_DIM, _d + 4096); } while (0)

#define STAGE_B(BUF, UN, KT) do { \
    const short* _s = bSrc + (long)(UN) * 32 * K_DIM + (long)(KT) * 64; \
    short* _d = Bs + (BUF) * 16384 + (UN) * 8192 + ldd; \
    gload_lds16(_s, _d); \
    gload_lds16(_s + (long)128 * K_DIM, _d + 4096); } while (0)

#define READ_A(BUF, MH) do { \
    const short* _p = As + (BUF) * 16384 + (MH) * 8192 + (wr * 64 + lr) * 64; \
    _Pragma("unroll") \
    for (int _mm = 0; _mm < 4; ++_mm) { \
        a[_mm * 2]     = *(const short8*)(_p + _mm * 1024 + ksw0); \
        a[_mm * 2 + 1] = *(const short8*)(_p + _mm * 1024 + ksw1); } } while (0)

#define READ_B(BUF, NH, BR) do { \
    const short* _p = Bs + (BUF) * 16384 + (NH) * 8192 + (wc * 32 + lr) * 64; \
    _Pragma("unroll") \
    for (int _nn = 0; _nn < 2; ++_nn) { \
        BR[_nn * 2]     = *(const short8*)(_p + _nn * 1024 + ksw0); \
        BR[_nn * 2 + 1] = *(const short8*)(_p + _nn * 1024 + ksw1); } } while (0)

#define MFMA_QUAD(MH, NH, BR) do { \
    _Pragma("unroll") \
    for (int _mm = 0; _mm < 4; ++_mm) \
    _Pragma("unroll") \
    for (int _nn = 0; _nn < 2; ++_nn) { \
        acc[(MH) * 4 + _mm][(NH) * 2 + _nn] = __builtin_amdgcn_mfma_f32_16x16x32_bf16( \
            a[_mm * 2], BR[_nn * 2], acc[(MH) * 4 + _mm][(NH) * 2 + _nn], 0, 0, 0); \
        acc[(MH) * 4 + _mm][(NH) * 2 + _nn] = __builtin_amdgcn_mfma_f32_16x16x32_bf16( \
            a[_mm * 2 + 1], BR[_nn * 2 + 1], acc[(MH) * 4 + _mm][(NH) * 2 + _nn], 0, 0, 0); } } while (0)

#define BAR()   asm volatile("s_barrier" ::: "memory")
#define LGKM0() asm volatile("s_waitcnt lgkmcnt(0)" ::: "memory")
#define LGKM8() asm volatile("s_waitcnt lgkmcnt(8)" ::: "memory")
#define VM6()   asm volatile("s_waitcnt vmcnt(6)" ::: "memory")
#define VM0()   asm volatile("s_waitcnt vmcnt(0)" ::: "memory")
#define PRIO1() __builtin_amdgcn_s_setprio(1)
#define PRIO0() __builtin_amdgcn_s_setprio(0)

    f32x4 acc[8][4];
    #pragma unroll
    for (int i = 0; i < 8; i++)
        #pragma unroll
        for (int j = 0; j < 4; j++)
            acc[i][j] = (f32x4){0.f, 0.f, 0.f, 0.f};

    short8 a[8], b0[4], b1[4];

    // ---- prologue: tile0 fully -> buf0, tile1 units u0A,u0B,u1B -> buf1
    // (tile1's A-unit1 is staged at P1 of iteration 0)
    STAGE_A(0, 0, 0); STAGE_B(0, 0, 0); STAGE_B(0, 1, 0); STAGE_A(0, 1, 0);
    STAGE_A(1, 0, 1); STAGE_B(1, 0, 1); STAGE_B(1, 1, 1);
    VM6();   // 14 issued, wait 8 oldest = all of tile 0
    BAR();

    for (int it = 0; it < ITERS; ++it) {
        int t1 = 2 * it + 1;
        int tn0 = 2 * it + 2, tn1 = 2 * it + 3;
        bool st = (it < ITERS - 1);

        // ---- P1: quadrant (0,0) of even tile (buf0)
        READ_A(0, 0);
        READ_B(0, 0, b0);
        STAGE_A(1, 1, t1);
        LGKM8();
        BAR(); LGKM0();
        PRIO1(); MFMA_QUAD(0, 0, b0); PRIO0();
        BAR();

        // ---- P2: (0,1)
        READ_B(0, 1, b1);
        if (st) STAGE_A(0, 0, tn0);
        BAR(); LGKM0();
        PRIO1(); MFMA_QUAD(0, 1, b1); PRIO0();
        BAR();

        // ---- P3: (1,1)
        READ_A(0, 1);
        if (st) STAGE_B(0, 0, tn0);
        BAR(); LGKM0();
        PRIO1(); MFMA_QUAD(1, 1, b1); PRIO0();
        BAR();

        // ---- P4: (1,0)  [vmcnt point]
        if (st) { STAGE_B(0, 1, tn0); VM6(); } else { VM0(); }
        BAR();
        PRIO1(); MFMA_QUAD(1, 0, b0); PRIO0();
        BAR();

        // ---- P5: quadrant (0,0) of odd tile (buf1)
        READ_A(1, 0);
        READ_B(1, 0, b0);
        if (st) STAGE_A(0, 1, tn0);
        LGKM8();
        BAR(); LGKM0();
        PRIO1(); MFMA_QUAD(0, 0, b0); PRIO0();
        BAR();

        // ---- P6: (0,1)
        READ_B(1, 1, b1);
        if (st) STAGE_A(1, 0, tn1);
        BAR(); LGKM0();
        PRIO1(); MFMA_QUAD(0, 1, b1); PRIO0();
        BAR();

        // ---- P7: (1,1)
        READ_A(1, 1);
        if (st) STAGE_B(1, 0, tn1);
        BAR(); LGKM0();
        PRIO1(); MFMA_QUAD(1, 1, b1); PRIO0();
        BAR();

        // ---- P8: (1,0)  [vmcnt point]
        if (st) { STAGE_B(1, 1, tn1); VM6(); }
        BAR();
        PRIO1(); MFMA_QUAD(1, 0, b0); PRIO0();
        BAR();
    }

    // ---- epilogue: C/D layout col = lane&15, row = (lane>>4)*4 + reg
    #pragma unroll
    for (int j = 0; j < 4; j++) {
        int col = n0 + wc * 64 + j * 16 + lr;
        float os = outscale[col];
        float bs = bias[col];
        #pragma unroll
        for (int i = 0; i < 8; i++) {
            int rbase = m0 + wr * 128 + i * 16 + lk * 4;
            #pragma unroll
            for (int r = 0; r < 4; r++) {
                C[(long)(rbase + r) * N_DIM + col] = acc[i][j][r] * os + bs;
            }
        }
    }
#undef STAGE_A
#undef STAGE_B
#undef READ_A
#undef READ_B
#undef MFMA_QUAD
}

// ---------------------------------------------------------------- launch
extern "C" void kernel_launch(void* const* d_in, const int* in_sizes, int n_in,
                              void* d_out, int out_size, void* d_ws, size_t ws_size,
                              hipStream_t stream) {
    const float* x      = (const float*)d_in[0];  // [4,2048,4096]
    const float* weight = (const float*)d_in[1];  // [4096,4096] int8-valued
    const float* wscale = (const float*)d_in[2];  // [1,1,4096]
    const float* bias   = (const float*)d_in[3];  // [4096]
    float* out = (float*)d_out;                   // [4,2048,4096]

    char* ws = (char*)d_ws;
    short* Abf      = (short*)ws;                                   // 64 MB
    short* Wbf      = (short*)(ws + (size_t)64 * 1024 * 1024);      // 32 MB
    float* partials = (float*)(ws + (size_t)96 * 1024 * 1024);      // 2048 f
    float* scal     = partials + 2048;                              // 2 f
    float* outsc    = scal + 16;                                    // 4096 f

    long n_x = (long)M_DIM * K_DIM;        // 33554432
    long n_w = (long)N_DIM * K_DIM;        // 16777216

    minmax_kernel<<<1024, 256, 0, stream>>>(x, n_x / 4, partials);
    finalize_kernel<<<1, 256, 0, stream>>>(partials, wscale, scal, outsc);
    quantize_kernel<<<2048, 256, 0, stream>>>(x, scal, (uint4*)Abf, n_x / 8);
    convw_kernel<<<1024, 256, 0, stream>>>(weight, (uint4*)Wbf, n_w / 8);

    int lds_bytes = 131072;  // 2 bufs x (A 32KB + B 32KB)
    (void)hipFuncSetAttribute((const void*)gemm_kernel,
                              hipFuncAttributeMaxDynamicSharedMemorySize,
                              lds_bytes);
    dim3 grid((M_DIM / BM) * (N_DIM / BN));  // 32*16 = 512
    gemm_kernel<<<grid, 512, lds_bytes, stream>>>(Abf, Wbf, outsc, bias, out);
}

// Round 5
// 206.464 us; speedup vs baseline: 2.0396x; 1.4475x over previous
//
#include <hip/hip_runtime.h>
#include <hip/hip_bf16.h>
#include <stdint.h>

typedef __attribute__((ext_vector_type(4))) int i32x4;

#define K_DIM 4096
#define M_DIM 8192
#define N_DIM 4096

#define BM 256
#define BN 256
#define BKB 128                  // K-bytes (=128 i8) per K-tile
#define K_TILES (K_DIM / BKB)    // 32
#define GITERS (K_TILES / 2)     // 16 iterations, 2 K-tiles each

// ---------------------------------------------------------------- helpers
__device__ __forceinline__ void gload_lds16(const void* g, void* l) {
    __builtin_amdgcn_global_load_lds(
        (__attribute__((address_space(1))) void*)(void*)g,
        (__attribute__((address_space(3))) void*)(void*)l,
        16, 0, 0);
}

// ---------------------------------------------------------------- kernel 1: min/max partials
__global__ void minmax_kernel(const float* __restrict__ x, long n4,
                              float* __restrict__ partials) {
    const float4* x4 = (const float4*)x;
    float mn = 1e30f, mx = -1e30f;
    long stride = (long)gridDim.x * blockDim.x;
    for (long i = (long)blockIdx.x * blockDim.x + threadIdx.x; i < n4; i += stride) {
        float4 v = x4[i];
        mn = fminf(mn, fminf(fminf(v.x, v.y), fminf(v.z, v.w)));
        mx = fmaxf(mx, fmaxf(fmaxf(v.x, v.y), fmaxf(v.z, v.w)));
    }
    #pragma unroll
    for (int off = 32; off; off >>= 1) {
        mn = fminf(mn, __shfl_down(mn, off));
        mx = fmaxf(mx, __shfl_down(mx, off));
    }
    __shared__ float smn[4], smx[4];
    int wid = threadIdx.x >> 6, lane = threadIdx.x & 63;
    if (lane == 0) { smn[wid] = mn; smx[wid] = mx; }
    __syncthreads();
    if (threadIdx.x == 0) {
        mn = fminf(fminf(smn[0], smn[1]), fminf(smn[2], smn[3]));
        mx = fmaxf(fmaxf(smx[0], smx[1]), fmaxf(smx[2], smx[3]));
        partials[blockIdx.x] = mn;
        partials[1024 + blockIdx.x] = mx;
    }
}

// ---------------------------------------------------------------- kernel 2: finalize scalars
__global__ void finalize_kernel(const float* __restrict__ partials,
                                float* __restrict__ scal) {
    float mn = 1e30f, mx = -1e30f;
    for (int i = threadIdx.x; i < 1024; i += 256) {
        mn = fminf(mn, partials[i]);
        mx = fmaxf(mx, partials[1024 + i]);
    }
    #pragma unroll
    for (int off = 32; off; off >>= 1) {
        mn = fminf(mn, __shfl_down(mn, off));
        mx = fmaxf(mx, __shfl_down(mx, off));
    }
    __shared__ float smn[4], smx[4];
    int wid = threadIdx.x >> 6, lane = threadIdx.x & 63;
    if (lane == 0) { smn[wid] = mn; smx[wid] = mx; }
    __syncthreads();
    if (threadIdx.x == 0) {
        mn = fminf(fminf(smn[0], smn[1]), fminf(smn[2], smn[3]));
        mx = fmaxf(fmaxf(smx[0], smx[1]), fmaxf(smx[2], smx[3]));
        float scale = (mx - mn) / 255.0f;
        float zp = rintf(-128.0f - mn / scale);
        zp = fminf(fmaxf(zp, -128.0f), 127.0f);
        scal[0] = scale;
        scal[1] = zp;
    }
}

// ---------------------------------------------------------------- kernel 3: quantize x -> i8
__global__ void quantize_kernel(const float* __restrict__ x,
                                const float* __restrict__ scal,
                                uint4* __restrict__ q, long n16) {
    float scale = scal[0];
    float zp = scal[1];
    long stride = (long)gridDim.x * blockDim.x;
    for (long i = (long)blockIdx.x * blockDim.x + threadIdx.x; i < n16; i += stride) {
        const float4* xp = (const float4*)x + i * 4;
        unsigned wrd[4];
        #pragma unroll
        for (int w = 0; w < 4; w++) {
            float4 v = xp[w];
            float e[4] = {v.x, v.y, v.z, v.w};
            unsigned word = 0;
            #pragma unroll
            for (int j = 0; j < 4; j++) {
                float qf = rintf(e[j] / scale + zp);          // matches reference rounding
                qf = fminf(fmaxf(qf, -128.0f), 127.0f);
                int iq = (int)qf;
                word |= ((unsigned)iq & 0xffu) << (8 * j);
            }
            wrd[w] = word;
        }
        uint4 o; o.x = wrd[0]; o.y = wrd[1]; o.z = wrd[2]; o.w = wrd[3];
        q[i] = o;
    }
}

// ---------------------------------------------------------------- kernel 4: weight fp32 -> i8 + rowsum
// One wave per row: 64 lanes x 64 floats = 4096 floats (full row coverage).
__global__ void convw_kernel(const float* __restrict__ w,
                             signed char* __restrict__ Wq,
                             int* __restrict__ rowsum) {
    int row = blockIdx.x * 4 + (threadIdx.x >> 6);   // 1024 blocks x 4 rows
    int lane = threadIdx.x & 63;
    const float4* src = (const float4*)(w + (long)row * K_DIM);  // 1024 float4/row
    uint4* dst = (uint4*)(Wq + (long)row * K_DIM);               // 256 uint4/row
    float s = 0.f;
    #pragma unroll
    for (int k = 0; k < 4; k++) {
        int u = k * 64 + lane;          // uint4 index 0..255
        unsigned wrd[4];
        #pragma unroll
        for (int j = 0; j < 4; j++) {
            float4 v = src[u * 4 + j];
            float e[4] = {v.x, v.y, v.z, v.w};
            unsigned word = 0;
            #pragma unroll
            for (int b = 0; b < 4; b++) {
                int iv = (int)e[b];                  // exact: integer-valued fp32
                s += e[b];
                word |= ((unsigned)iv & 0xffu) << (8 * b);
            }
            wrd[j] = word;
        }
        uint4 o; o.x = wrd[0]; o.y = wrd[1]; o.z = wrd[2]; o.w = wrd[3];
        dst[u] = o;
    }
    #pragma unroll
    for (int off = 32; off; off >>= 1) s += __shfl_down(s, off);
    if (lane == 0) rowsum[row] = (int)s;             // exact: |sum| < 2^24
}

// ---------------------------------------------------------------- kernel 5: fold epilogue coefficients
__global__ void fold_kernel(const float* __restrict__ scal,
                            const int* __restrict__ rowsum,
                            const float* __restrict__ wscale,
                            const float* __restrict__ bias,
                            float* __restrict__ outscale,
                            float* __restrict__ bias2) {
    int n = blockIdx.x * 256 + threadIdx.x;          // 16 blocks x 256 = 4096
    float scale = scal[0], zp = scal[1];
    float os = scale * wscale[n];
    outscale[n] = os;
    bias2[n] = bias[n] - zp * (float)rowsum[n] * os;
}

// ---------------------------------------------------------------- kernel 6: i8 GEMM, 8-phase
// Byte-identical structure to the verified round-3 bf16 kernel: 256x256 tile,
// K-tile = 128 B (now 128 i8 instead of 64 bf16), 512 threads (8 waves 2Mx4N),
// 2 K-tile LDS buffers (128 KiB), 8 phases/iter, counted vmcnt(6), setprio,
// 16B-slot XOR swizzle (inverse-permuted global source + swizzled ds_read).
// A/B fragments read with identical byte->k mappings, so any consistent
// per-lane k permutation of the i8 MFMA is correctness-neutral.
__global__ __launch_bounds__(512, 2) void gemm_kernel(
    const signed char* __restrict__ A,   // [8192][4096] i8 (q, zp NOT subtracted)
    const signed char* __restrict__ W,   // [4096][4096] i8
    const float* __restrict__ outscale,
    const float* __restrict__ bias2,
    float* __restrict__ C) {
    extern __shared__ char lds[];
    char* As = lds;            // 2 bufs x 32768 B (2 units x 128 rows x 128 B)
    char* Bs = lds + 65536;

    // XCD-aware swizzle (nwg = 512, divisible by 8)
    int nwg = gridDim.x;
    int cpx = nwg >> 3;
    int bid = blockIdx.x;
    int wg = (bid & 7) * cpx + (bid >> 3);
    int tm = wg >> 4;   // 32 M-tiles
    int tn = wg & 15;   // 16 N-tiles
    int m0 = tm * BM, n0 = tn * BN;

    int t = threadIdx.x;
    int wid = t >> 6, lane = t & 63;
    int wr = wid >> 2, wc = wid & 3;      // 2 x 4 wave grid
    int lr = lane & 15, lk = lane >> 4;
    int ksw0 = (lk ^ (lr & 7)) * 16;          // byte offset, khalf0 (k 0..63)
    int ksw1 = ((4 + lk) ^ (lr & 7)) * 16;    // khalf1 (k 64..127)

    // staging source geometry (byte units)
    int R0 = t >> 3;                              // 0..63
    int csw = ((t & 7) ^ ((t >> 3) & 7)) * 16;    // inverse-swizzled source col (B)
    const signed char* aSrc = A + (long)(m0 + R0) * K_DIM + csw;
    const signed char* bSrc = W + (long)(n0 + ((R0 >> 5) << 6) + (R0 & 31)) * K_DIM + csw;
    int ldd = t * 16;                             // lds dest bytes

#define STAGE_A(BUF, UN, KT) do { \
    const signed char* _s = aSrc + (long)(UN) * 64 * K_DIM + (long)(KT) * BKB; \
    char* _d = As + (BUF) * 32768 + (UN) * 16384 + ldd; \
    gload_lds16(_s, _d); \
    gload_lds16(_s + (long)128 * K_DIM, _d + 8192); } while (0)

#define STAGE_B(BUF, UN, KT) do { \
    const signed char* _s = bSrc + (long)(UN) * 32 * K_DIM + (long)(KT) * BKB; \
    char* _d = Bs + (BUF) * 32768 + (UN) * 16384 + ldd; \
    gload_lds16(_s, _d); \
    gload_lds16(_s + (long)128 * K_DIM, _d + 8192); } while (0)

#define READ_A(BUF, MH) do { \
    const char* _p = As + (BUF) * 32768 + (MH) * 16384 + (wr * 64 + lr) * 128; \
    _Pragma("unroll") \
    for (int _mm = 0; _mm < 4; ++_mm) { \
        a[_mm * 2]     = *(const i32x4*)(_p + _mm * 2048 + ksw0); \
        a[_mm * 2 + 1] = *(const i32x4*)(_p + _mm * 2048 + ksw1); } } while (0)

#define READ_B(BUF, NH, BR) do { \
    const char* _p = Bs + (BUF) * 32768 + (NH) * 16384 + (wc * 32 + lr) * 128; \
    _Pragma("unroll") \
    for (int _nn = 0; _nn < 2; ++_nn) { \
        BR[_nn * 2]     = *(const i32x4*)(_p + _nn * 2048 + ksw0); \
        BR[_nn * 2 + 1] = *(const i32x4*)(_p + _nn * 2048 + ksw1); } } while (0)

#define MFMA_QUAD(MH, NH, BR) do { \
    _Pragma("unroll") \
    for (int _mm = 0; _mm < 4; ++_mm) \
    _Pragma("unroll") \
    for (int _nn = 0; _nn < 2; ++_nn) { \
        acc[(MH) * 4 + _mm][(NH) * 2 + _nn] = __builtin_amdgcn_mfma_i32_16x16x64_i8( \
            a[_mm * 2], BR[_nn * 2], acc[(MH) * 4 + _mm][(NH) * 2 + _nn], 0, 0, 0); \
        acc[(MH) * 4 + _mm][(NH) * 2 + _nn] = __builtin_amdgcn_mfma_i32_16x16x64_i8( \
            a[_mm * 2 + 1], BR[_nn * 2 + 1], acc[(MH) * 4 + _mm][(NH) * 2 + _nn], 0, 0, 0); } } while (0)

#define BAR()   asm volatile("s_barrier" ::: "memory")
#define LGKM0() asm volatile("s_waitcnt lgkmcnt(0)" ::: "memory")
#define LGKM8() asm volatile("s_waitcnt lgkmcnt(8)" ::: "memory")
#define VM6()   asm volatile("s_waitcnt vmcnt(6)" ::: "memory")
#define VM0()   asm volatile("s_waitcnt vmcnt(0)" ::: "memory")
#define PRIO1() __builtin_amdgcn_s_setprio(1)
#define PRIO0() __builtin_amdgcn_s_setprio(0)

    i32x4 acc[8][4];
    #pragma unroll
    for (int i = 0; i < 8; i++)
        #pragma unroll
        for (int j = 0; j < 4; j++)
            acc[i][j] = (i32x4){0, 0, 0, 0};

    i32x4 a[8], b0[4], b1[4];

    // ---- prologue: tile0 fully -> buf0, tile1 units u0A,u0B,u1B -> buf1
    STAGE_A(0, 0, 0); STAGE_B(0, 0, 0); STAGE_B(0, 1, 0); STAGE_A(0, 1, 0);
    STAGE_A(1, 0, 1); STAGE_B(1, 0, 1); STAGE_B(1, 1, 1);
    VM6();   // 14 issued, wait 8 oldest = all of tile 0
    BAR();

    for (int it = 0; it < GITERS; ++it) {
        int t1 = 2 * it + 1;
        int tn0 = 2 * it + 2, tn1 = 2 * it + 3;
        bool st = (it < GITERS - 1);

        // ---- P1: quadrant (0,0) of even tile (buf0)
        READ_A(0, 0);
        READ_B(0, 0, b0);
        STAGE_A(1, 1, t1);
        LGKM8();
        BAR(); LGKM0();
        PRIO1(); MFMA_QUAD(0, 0, b0); PRIO0();
        BAR();

        // ---- P2: (0,1)
        READ_B(0, 1, b1);
        if (st) STAGE_A(0, 0, tn0);
        BAR(); LGKM0();
        PRIO1(); MFMA_QUAD(0, 1, b1); PRIO0();
        BAR();

        // ---- P3: (1,1)
        READ_A(0, 1);
        if (st) STAGE_B(0, 0, tn0);
        BAR(); LGKM0();
        PRIO1(); MFMA_QUAD(1, 1, b1); PRIO0();
        BAR();

        // ---- P4: (1,0)  [vmcnt point]
        if (st) { STAGE_B(0, 1, tn0); VM6(); } else { VM0(); }
        BAR();
        PRIO1(); MFMA_QUAD(1, 0, b0); PRIO0();
        BAR();

        // ---- P5: quadrant (0,0) of odd tile (buf1)
        READ_A(1, 0);
        READ_B(1, 0, b0);
        if (st) STAGE_A(0, 1, tn0);
        LGKM8();
        BAR(); LGKM0();
        PRIO1(); MFMA_QUAD(0, 0, b0); PRIO0();
        BAR();

        // ---- P6: (0,1)
        READ_B(1, 1, b1);
        if (st) STAGE_A(1, 0, tn1);
        BAR(); LGKM0();
        PRIO1(); MFMA_QUAD(0, 1, b1); PRIO0();
        BAR();

        // ---- P7: (1,1)
        READ_A(1, 1);
        if (st) STAGE_B(1, 0, tn1);
        BAR(); LGKM0();
        PRIO1(); MFMA_QUAD(1, 1, b1); PRIO0();
        BAR();

        // ---- P8: (1,0)  [vmcnt point]
        if (st) { STAGE_B(1, 1, tn1); VM6(); }
        BAR();
        PRIO1(); MFMA_QUAD(1, 0, b0); PRIO0();
        BAR();
    }

    // ---- epilogue: C/D layout col = lane&15, row = (lane>>4)*4 + reg
    #pragma unroll
    for (int j = 0; j < 4; j++) {
        int col = n0 + wc * 64 + j * 16 + lr;
        float os = outscale[col];
        float bs = bias2[col];
        #pragma unroll
        for (int i = 0; i < 8; i++) {
            int rbase = m0 + wr * 128 + i * 16 + lk * 4;
            #pragma unroll
            for (int r = 0; r < 4; r++) {
                C[(long)(rbase + r) * N_DIM + col] = (float)acc[i][j][r] * os + bs;
            }
        }
    }
#undef STAGE_A
#undef STAGE_B
#undef READ_A
#undef READ_B
#undef MFMA_QUAD
}

// ---------------------------------------------------------------- launch
extern "C" void kernel_launch(void* const* d_in, const int* in_sizes, int n_in,
                              void* d_out, int out_size, void* d_ws, size_t ws_size,
                              hipStream_t stream) {
    const float* x      = (const float*)d_in[0];  // [4,2048,4096]
    const float* weight = (const float*)d_in[1];  // [4096,4096] int8-valued
    const float* wscale = (const float*)d_in[2];  // [1,1,4096]
    const float* bias   = (const float*)d_in[3];  // [4096]
    float* out = (float*)d_out;                   // [4,2048,4096]

    char* ws = (char*)d_ws;
    signed char* Aq = (signed char*)ws;                             // 32 MB
    signed char* Wq = (signed char*)(ws + (size_t)32 * 1024 * 1024);// 16 MB
    float* partials = (float*)(ws + (size_t)48 * 1024 * 1024);      // 2048 f
    float* scal     = partials + 2048;                              // 2 f
    int*   rowsum   = (int*)(scal + 16);                            // 4096 i
    float* outsc    = (float*)(rowsum + 4096);                      // 4096 f
    float* bias2    = outsc + 4096;                                 // 4096 f

    long n_x = (long)M_DIM * K_DIM;        // 33554432

    minmax_kernel<<<1024, 256, 0, stream>>>(x, n_x / 4, partials);
    finalize_kernel<<<1, 256, 0, stream>>>(partials, scal);
    quantize_kernel<<<2048, 256, 0, stream>>>(x, scal, (uint4*)Aq, n_x / 16);
    convw_kernel<<<1024, 256, 0, stream>>>(weight, Wq, rowsum);
    fold_kernel<<<16, 256, 0, stream>>>(scal, rowsum, wscale, bias, outsc, bias2);

    int lds_bytes = 131072;  // 2 bufs x (A 32KB + B 32KB)
    (void)hipFuncSetAttribute((const void*)gemm_kernel,
                              hipFuncAttributeMaxDynamicSharedMemorySize,
                              lds_bytes);
    dim3 grid((M_DIM / BM) * (N_DIM / BN));  // 32*16 = 512
    gemm_kernel<<<grid, 512, lds_bytes, stream>>>(Aq, Wq, outsc, bias2, out);
}